// Round 13
// baseline (204.532 us; speedup 1.0000x reference)
//
#include <hip/hip_runtime.h>
#include <math.h>

#define N_IN  128
#define N_HID 128
#define N_OUT 64
#define NW    256    // dst windows (~196 nodes each; requires n <= NW*WMAX)
#define WMAX  256    // max nodes per window
#define WCAP  768    // capacity per (window, xcd-lane); mean ~294, >25 sigma
#define NLANE 8

typedef _Float16 f16x8 __attribute__((ext_vector_type(8)));
typedef float f32x4 __attribute__((ext_vector_type(4)));
typedef int i32x4 __attribute__((ext_vector_type(4)));

__device__ inline int win_of(int d, int n) { return (int)((long long)d * NW / n); }
__device__ inline int win_lo(int w, int n) {
  return (int)(((long long)w * n + NW - 1) / NW);
}

// ---------------- W fragment pack helper ----------------
__device__ inline void pack_one(const float* __restrict__ W, _Float16* __restrict__ Wp,
                                int N, int K, int idx) {
  int l = idx & 63;
  int ts = idx >> 6;
  int KS = K / 32;
  int t = ts / KS, s = ts - t * KS;
  int col = t * 16 + (l & 15);
  int k0 = s * 32 + (l >> 4) * 8;
  f16x8 f;
#pragma unroll
  for (int j = 0; j < 8; ++j) f[j] = (_Float16)W[(size_t)(k0 + j) * N + col];
  *reinterpret_cast<f16x8*>(&Wp[(size_t)idx * 8]) = f;
}

// ---- Phase A: partition edges into (window, xcd-lane) buckets + weight pack ----
__global__ __launch_bounds__(256) void k_part_pack(
    const int* __restrict__ dst, const int* __restrict__ src, int E, int n,
    int* __restrict__ bcur, int2* __restrict__ bkt, int pb,
    const float* __restrict__ W1, const float* __restrict__ W2,
    const float* __restrict__ W3, _Float16* __restrict__ Wp1,
    _Float16* __restrict__ Wp2, _Float16* __restrict__ Wp3) {
  if (blockIdx.x >= pb) {
    int idx = (int)(blockIdx.x - pb) * 256 + threadIdx.x;
    if (idx < 2048) pack_one(W1, Wp1, N_HID, N_IN, idx);
    else if (idx < 4096) pack_one(W2, Wp2, N_HID, N_HID, idx - 2048);
    else if (idx < 5120) pack_one(W3, Wp3, N_OUT, N_HID, idx - 4096);
    return;
  }
  int lane = blockIdx.x & (NLANE - 1);
  int start = (blockIdx.x * 256 + threadIdx.x) * 4;
  int stride = pb * 256 * 4;
  for (int i0 = start; i0 + 4 <= E; i0 += stride) {
    i32x4 d = __builtin_nontemporal_load(reinterpret_cast<const i32x4*>(&dst[i0]));
    i32x4 s = __builtin_nontemporal_load(reinterpret_cast<const i32x4*>(&src[i0]));
    int dd[4] = {d.x, d.y, d.z, d.w};
    int ss[4] = {s.x, s.y, s.z, s.w};
#pragma unroll
    for (int u = 0; u < 4; ++u) {
      int b = win_of(dd[u], n) * NLANE + lane;
      int slot = atomicAdd(&bcur[b], 1);
      if (slot < WCAP) bkt[(size_t)b * WCAP + slot] = make_int2(dd[u], ss[u]);
    }
  }
  if (blockIdx.x == 0 && threadIdx.x == 0)
    for (int i = E & ~3; i < E; ++i) {
      int b = win_of(dst[i], n) * NLANE;
      int slot = atomicAdd(&bcur[b], 1);
      if (slot < WCAP) bkt[(size_t)b * WCAP + slot] = make_int2(dst[i], src[i]);
    }
}

// ---- Phase B: per-window LDS histogram -> cnt (coalesced write, no global atomics) ----
__global__ __launch_bounds__(256) void k_whist(
    const int* __restrict__ bcur, const int2* __restrict__ bkt, int n,
    int* __restrict__ cnt) {
  __shared__ int hcnt[WMAX];
  int w = blockIdx.x;
  int lo = win_lo(w, n);
  int hi = win_lo(w + 1, n);
  for (int i = threadIdx.x; i < WMAX; i += 256) hcnt[i] = 0;
  __syncthreads();
  for (int l = 0; l < NLANE; ++l) {
    int len = min(bcur[w * NLANE + l], WCAP);
    const int2* base = &bkt[(size_t)(w * NLANE + l) * WCAP];
    for (int i = threadIdx.x; i < len; i += 256)
      atomicAdd(&hcnt[base[i].x - lo], 1);
  }
  __syncthreads();
  for (int i = threadIdx.x; i < hi - lo; i += 256) cnt[lo + i] = hcnt[i];
}

// ---- scan: block b redundantly sums cnt[0..b*512), scans own chunk. Full parallel. ----
#define SCHUNK 512
__global__ __launch_bounds__(SCHUNK) void k_scan_all(
    const int* __restrict__ cnt, int n, int E,
    int* __restrict__ rowptr, float* __restrict__ dinv) {
  __shared__ int sh[SCHUNK];
  int t = threadIdx.x;
  int base = blockIdx.x * SCHUNK;
  int pre = 0;
  for (int i = t; i < base; i += SCHUNK) pre += cnt[i];
  sh[t] = pre;
  __syncthreads();
  for (int o = SCHUNK / 2; o > 0; o >>= 1) {
    if (t < o) sh[t] += sh[t + o];
    __syncthreads();
  }
  int blockpre = sh[0];
  __syncthreads();
  int v = (base + t < n) ? cnt[base + t] : 0;
  sh[t] = v;
  __syncthreads();
  for (int o = 1; o < SCHUNK; o <<= 1) {
    int u = (t >= o) ? sh[t - o] : 0;
    __syncthreads();
    sh[t] += u;
    __syncthreads();
  }
  int i = base + t;
  if (i < n) {
    rowptr[i] = blockpre + sh[t] - v;          // exclusive
    dinv[i] = rsqrtf((float)v + 1.0f);         // +1 self loop
    if (i == n - 1) rowptr[n] = E;
  }
}

// ---------------- MFMA GEMM body (fp32 A via NT loads, dinv scale, out fp16) ----------
__device__ inline void gemm1_body(int bid, const float* __restrict__ A,
                                  const _Float16* __restrict__ Wp,
                                  const float* __restrict__ dinv,
                                  _Float16* __restrict__ out, int M) {
  constexpr int N = N_HID, K = 128, KS = K / 32, NT = N / 16;
  int lane = threadIdx.x & 63;
  int wave = threadIdx.x >> 6;
  int rowbase = bid * 64 + wave * 16;
  int arow = rowbase + (lane & 15);
  int arc = arow < M ? arow : M - 1;
  int k0 = (lane >> 4) * 8;

  f16x8 afrag[KS];
#pragma unroll
  for (int s = 0; s < KS; ++s) {
    f32x4 v0 = __builtin_nontemporal_load(
        reinterpret_cast<const f32x4*>(&A[(size_t)arc * K + s * 32 + k0]));
    f32x4 v1 = __builtin_nontemporal_load(
        reinterpret_cast<const f32x4*>(&A[(size_t)arc * K + s * 32 + k0 + 4]));
    f16x8 f;
    f[0] = (_Float16)v0.x; f[1] = (_Float16)v0.y;
    f[2] = (_Float16)v0.z; f[3] = (_Float16)v0.w;
    f[4] = (_Float16)v1.x; f[5] = (_Float16)v1.y;
    f[6] = (_Float16)v1.z; f[7] = (_Float16)v1.w;
    afrag[s] = f;
  }

  f32x4 acc[NT] = {};
#pragma unroll
  for (int t = 0; t < NT; ++t)
#pragma unroll
    for (int s = 0; s < KS; ++s) {
      f16x8 b = *reinterpret_cast<const f16x8*>(&Wp[((size_t)(t * KS + s) * 64 + lane) * 8]);
      acc[t] = __builtin_amdgcn_mfma_f32_16x16x32_f16(afrag[s], b, acc[t], 0, 0, 0);
    }

  int crow = (lane >> 4) * 4;
  int col = lane & 15;
#pragma unroll
  for (int r = 0; r < 4; ++r) {
    int grow = rowbase + crow + r;
    if (grow < M) {
      float dv = dinv[grow];
#pragma unroll
      for (int t = 0; t < NT; ++t)
        out[(size_t)grow * N + t * 16 + col] = (_Float16)(acc[t][r] * dv);
    }
  }
}

// ---- Phase C: per-window CSR fill from buckets (LDS cursors, private csr window)
//      + gemm1 riders (blocks >= NW) ----
__global__ __launch_bounds__(256) void k_wfill_gemm1(
    const int* __restrict__ bcur, const int2* __restrict__ bkt, int n,
    const int* __restrict__ rowptr, unsigned short* __restrict__ csr,
    const float* __restrict__ x, const _Float16* __restrict__ Wp1,
    const float* __restrict__ dinv, _Float16* __restrict__ hs1) {
  if (blockIdx.x >= NW) {
    gemm1_body((int)blockIdx.x - NW, x, Wp1, dinv, hs1, n);
    return;
  }
  __shared__ int rowL[WMAX];
  __shared__ int curL[WMAX];
  int w = blockIdx.x;
  int lo = win_lo(w, n);
  int hi = win_lo(w + 1, n);
  for (int i = threadIdx.x; i < hi - lo; i += 256) {
    rowL[i] = rowptr[lo + i];
    curL[i] = 0;
  }
  __syncthreads();
  for (int l = 0; l < NLANE; ++l) {
    int len = min(bcur[w * NLANE + l], WCAP);
    const int2* base = &bkt[(size_t)(w * NLANE + l) * WCAP];
    for (int i = threadIdx.x; i < len; i += 256) {
      int2 e = base[i];
      int li = e.x - lo;
      int pos = rowL[li] + atomicAdd(&curL[li], 1);
      csr[pos] = (unsigned short)e.y;
    }
  }
}

// ---------------- Fused aggregation + GEMM, quarter-wave f16x8 gather ----------------
template <int NOUT>
__global__ __launch_bounds__(256) void k_agg_gemm(
    const _Float16* __restrict__ hs, const float* __restrict__ dinv,
    const int* __restrict__ rowptr, const unsigned short* __restrict__ csr,
    const float* __restrict__ bias, const _Float16* __restrict__ Wp,
    _Float16* __restrict__ out, int n, int E) {
  constexpr int D = 128, KS = 4, NT = NOUT / 16, TPW = NT / 4;
  __shared__ __align__(16) _Float16 sm[16][D + 8];  // 272B row stride
  int lane = threadIdx.x & 63, wave = threadIdx.x >> 6;
  int q = lane >> 4;   // quarter-wave: one node per quarter
  int j = lane & 15;   // dim slot [8j, 8j+8)
  int nodebase = blockIdx.x * 16;
  int node = nodebase + wave * 4 + q;
  int cn = min(node, n - 1);
  bool valid = node < n;
  int beg = rowptr[cn], end = valid ? rowptr[cn + 1] : beg;

  float acc[8];
  {
    f16x8 sv = *reinterpret_cast<const f16x8*>(&hs[(size_t)cn * D + 8 * j]);
#pragma unroll
    for (int k = 0; k < 8; ++k) acc[k] = valid ? (float)sv[k] : 0.f;
  }

  for (int e = beg; e < end; e += 4) {
    int idx[4];
    float wt[4];
#pragma unroll
    for (int u = 0; u < 4; ++u) {
      int p = e + u;
      wt[u] = p < end ? 1.f : 0.f;
      idx[u] = csr[min(p, E - 1)];
    }
    f16x8 v[4];
#pragma unroll
    for (int u = 0; u < 4; ++u)
      v[u] = *reinterpret_cast<const f16x8*>(&hs[(size_t)idx[u] * D + 8 * j]);
#pragma unroll
    for (int u = 0; u < 4; ++u)
#pragma unroll
      for (int k = 0; k < 8; ++k)
        acc[k] = fmaf(wt[u], (float)v[u][k], acc[k]);
  }

  // dinv*acc + bias, relu -> LDS tile
  {
    float4 bv0 = *reinterpret_cast<const float4*>(&bias[8 * j]);
    float4 bv1 = *reinterpret_cast<const float4*>(&bias[8 * j + 4]);
    float bp[8] = {bv0.x, bv0.y, bv0.z, bv0.w, bv1.x, bv1.y, bv1.z, bv1.w};
    float dv = dinv[cn];
    f16x8 pv;
#pragma unroll
    for (int k = 0; k < 8; ++k) pv[k] = (_Float16)fmaxf(dv * acc[k] + bp[k], 0.f);
    *reinterpret_cast<f16x8*>(&sm[wave * 4 + q][8 * j]) = pv;
  }
  __syncthreads();

  // MFMA: 16-row tile @ Wp; wave handles TPW n-tiles
  int r = lane & 15, k0 = (lane >> 4) * 8;
  f16x8 af[KS];
#pragma unroll
  for (int s = 0; s < KS; ++s)
    af[s] = *reinterpret_cast<const f16x8*>(&sm[r][s * 32 + k0]);

  f32x4 acc2[TPW] = {};
#pragma unroll
  for (int tt = 0; tt < TPW; ++tt) {
    int t = wave * TPW + tt;
#pragma unroll
    for (int s = 0; s < KS; ++s) {
      f16x8 b = *reinterpret_cast<const f16x8*>(&Wp[((size_t)(t * KS + s) * 64 + lane) * 8]);
      acc2[tt] = __builtin_amdgcn_mfma_f32_16x16x32_f16(af[s], b, acc2[tt], 0, 0, 0);
    }
  }

  int crow = (lane >> 4) * 4, col = lane & 15;
#pragma unroll
  for (int r4 = 0; r4 < 4; ++r4) {
    int gnode = nodebase + crow + r4;
    if (gnode < n) {
      float dv = dinv[gnode];
#pragma unroll
      for (int tt = 0; tt < TPW; ++tt)
        out[(size_t)gnode * NOUT + (wave * TPW + tt) * 16 + col] =
            (_Float16)(acc2[tt][r4] * dv);
    }
  }
}

// ---------------- Aggregation D=64 + log_softmax, eighth-wave f16x8 gather ----------
__global__ __launch_bounds__(256) void k_agg64_lsm(
    const _Float16* __restrict__ hs, const float* __restrict__ dinv,
    const int* __restrict__ rowptr, const unsigned short* __restrict__ csr,
    const float* __restrict__ bias, float* __restrict__ out, int n, int E) {
  constexpr int D = 64;
  int lane = threadIdx.x & 63, wave = threadIdx.x >> 6;
  int g = lane >> 3;   // eighth-wave group: one node per group
  int j = lane & 7;    // dim slot [8j, 8j+8)
  int node = blockIdx.x * 32 + wave * 8 + g;
  int cn = min(node, n - 1);
  bool valid = node < n;
  int beg = rowptr[cn], end = valid ? rowptr[cn + 1] : beg;

  float acc[8];
  {
    f16x8 sv = *reinterpret_cast<const f16x8*>(&hs[(size_t)cn * D + 8 * j]);
#pragma unroll
    for (int k = 0; k < 8; ++k) acc[k] = valid ? (float)sv[k] : 0.f;
  }

  for (int e = beg; e < end; e += 4) {
    int idx[4];
    float wt[4];
#pragma unroll
    for (int u = 0; u < 4; ++u) {
      int p = e + u;
      wt[u] = p < end ? 1.f : 0.f;
      idx[u] = csr[min(p, E - 1)];
    }
    f16x8 v[4];
#pragma unroll
    for (int u = 0; u < 4; ++u)
      v[u] = *reinterpret_cast<const f16x8*>(&hs[(size_t)idx[u] * D + 8 * j]);
#pragma unroll
    for (int u = 0; u < 4; ++u)
#pragma unroll
      for (int k = 0; k < 8; ++k)
        acc[k] = fmaf(wt[u], (float)v[u][k], acc[k]);
  }

  float dv = dinv[cn];
  float val[8];
  {
    float4 bv0 = *reinterpret_cast<const float4*>(&bias[8 * j]);
    float4 bv1 = *reinterpret_cast<const float4*>(&bias[8 * j + 4]);
    float bp[8] = {bv0.x, bv0.y, bv0.z, bv0.w, bv1.x, bv1.y, bv1.z, bv1.w};
#pragma unroll
    for (int k = 0; k < 8; ++k) val[k] = dv * acc[k] + bp[k];
  }

  // log_softmax: 8 dims/lane x 8 lanes (xor offsets < 8 stay in-group)
  float m = val[0];
#pragma unroll
  for (int k = 1; k < 8; ++k) m = fmaxf(m, val[k]);
#pragma unroll
  for (int o = 4; o > 0; o >>= 1) m = fmaxf(m, __shfl_xor(m, o));
  float ss = 0.f;
#pragma unroll
  for (int k = 0; k < 8; ++k) ss += expf(val[k] - m);
#pragma unroll
  for (int o = 4; o > 0; o >>= 1) ss += __shfl_xor(ss, o);
  float lse = m + logf(ss);

  if (valid) {
    f32x4 o0 = {val[0] - lse, val[1] - lse, val[2] - lse, val[3] - lse};
    f32x4 o1 = {val[4] - lse, val[5] - lse, val[6] - lse, val[7] - lse};
    __builtin_nontemporal_store(o0, reinterpret_cast<f32x4*>(&out[(size_t)node * D + 8 * j]));
    __builtin_nontemporal_store(o1, reinterpret_cast<f32x4*>(&out[(size_t)node * D + 8 * j + 4]));
  }
}

// ---------------- launch ----------------
extern "C" void kernel_launch(void* const* d_in, const int* in_sizes, int n_in,
                              void* d_out, int out_size, void* d_ws, size_t ws_size,
                              hipStream_t stream) {
  const float* x  = (const float*)d_in[0];
  const float* W1 = (const float*)d_in[1];
  const float* b1 = (const float*)d_in[2];
  const float* W2 = (const float*)d_in[3];
  const float* b2 = (const float*)d_in[4];
  const float* W3 = (const float*)d_in[5];
  const float* b3 = (const float*)d_in[6];
  const int*   ei = (const int*)d_in[7];

  int n = in_sizes[0] / N_IN;   // 50000 (< 65536: uint16 csr + NW*WMAX window map)
  int E = in_sizes[7] / 2;
  const int* src = ei;
  const int* dst = ei + E;

  char* w = (char*)d_ws;
  size_t off = 0;
  auto alloc = [&](size_t bytes) -> void* {
    void* p = w + off;
    off = (off + bytes + 255) & ~(size_t)255;
    return p;
  };
  _Float16* hs1 = (_Float16*)alloc((size_t)n * N_HID * sizeof(_Float16));
  _Float16* hs2 = (_Float16*)alloc((size_t)n * N_HID * sizeof(_Float16));
  _Float16* hs3 = (_Float16*)alloc((size_t)n * N_OUT * sizeof(_Float16));
  _Float16* Wp1 = (_Float16*)alloc((size_t)N_IN * N_HID * sizeof(_Float16));
  _Float16* Wp2 = (_Float16*)alloc((size_t)N_HID * N_HID * sizeof(_Float16));
  _Float16* Wp3 = (_Float16*)alloc((size_t)N_HID * N_OUT * sizeof(_Float16));
  float* dinv = (float*)alloc((size_t)n * sizeof(float));
  int* cnt = (int*)alloc((size_t)n * sizeof(int));
  int* rowptr = (int*)alloc((size_t)(n + 1) * sizeof(int));
  unsigned short* csr = (unsigned short*)alloc((size_t)E * sizeof(unsigned short));
  int* bcur = (int*)alloc((size_t)NW * NLANE * sizeof(int));
  int2* bkt = (int2*)alloc((size_t)NW * NLANE * WCAP * sizeof(int2));

  // ---- bucket partition (+ weight pack riders) ----
  hipMemsetAsync(bcur, 0, (size_t)NW * NLANE * sizeof(int), stream);
  int pb = 1024;  // multiple of NLANE
  k_part_pack<<<pb + 20, 256, 0, stream>>>(dst, src, E, n, bcur, bkt, pb,
                                           W1, W2, W3, Wp1, Wp2, Wp3);
  // ---- per-window LDS hist -> cnt ----
  k_whist<<<NW, 256, 0, stream>>>(bcur, bkt, n, cnt);
  // ---- scan -> rowptr, dinv ----
  int nb = (n + SCHUNK - 1) / SCHUNK;
  k_scan_all<<<nb, SCHUNK, 0, stream>>>(cnt, n, E, rowptr, dinv);
  // ---- per-window CSR fill (+ gemm1 riders) ----
  int gb = (n + 63) / 64;
  k_wfill_gemm1<<<NW + gb, 256, 0, stream>>>(bcur, bkt, n, rowptr, csr,
                                             x, Wp1, dinv, hs1);

  int ab = (n + 15) / 16;
  int ab64 = (n + 31) / 32;
  k_agg_gemm<N_HID><<<ab, 256, 0, stream>>>(hs1, dinv, rowptr, csr, b1, Wp2, hs2, n, E);
  k_agg_gemm<N_OUT><<<ab, 256, 0, stream>>>(hs2, dinv, rowptr, csr, b2, Wp3, hs3, n, E);
  k_agg64_lsm<<<ab64, 256, 0, stream>>>(hs3, dinv, rowptr, csr, b3, (float*)d_out, n, E);
}

// Round 14
// 145.826 us; speedup vs baseline: 1.4026x; 1.4026x over previous
//
#include <hip/hip_runtime.h>
#include <math.h>

#define N_IN  128
#define N_HID 128
#define N_OUT 64

typedef _Float16 f16x8 __attribute__((ext_vector_type(8)));
typedef float f32x4 __attribute__((ext_vector_type(4)));
typedef int i32x4 __attribute__((ext_vector_type(4)));
typedef unsigned short u16x4 __attribute__((ext_vector_type(4)));

// ---------------- W fragment pack helper ----------------
// frag elem j of lane l, k-step s, n-tile t = W[s*32 + (l>>4)*8 + j][t*16 + (l&15)]
__device__ inline void pack_one(const float* __restrict__ W, _Float16* __restrict__ Wp,
                                int N, int K, int idx) {
  int l = idx & 63;
  int ts = idx >> 6;
  int KS = K / 32;
  int t = ts / KS, s = ts - t * KS;
  int col = t * 16 + (l & 15);
  int k0 = s * 32 + (l >> 4) * 8;
  f16x8 f;
#pragma unroll
  for (int j = 0; j < 8; ++j) f[j] = (_Float16)W[(size_t)(k0 + j) * N + col];
  *reinterpret_cast<f16x8*>(&Wp[(size_t)idx * 8]) = f;
}

// ---- hist + rank capture (blocks < hb) + weight pack (blocks >= hb) ----
// rank[i] = this edge's arrival index within its dst row; makes fill atomic-free.
__global__ void k_hist_rank_pack(const int* __restrict__ dst, int E, int n,
                                 int* __restrict__ cnt, unsigned short* __restrict__ rank,
                                 int hb,
                                 const float* __restrict__ W1, const float* __restrict__ W2,
                                 const float* __restrict__ W3, _Float16* __restrict__ Wp1,
                                 _Float16* __restrict__ Wp2, _Float16* __restrict__ Wp3) {
  if (blockIdx.x >= hb) {
    int idx = (int)(blockIdx.x - hb) * 256 + threadIdx.x;
    if (idx < 2048) pack_one(W1, Wp1, N_HID, N_IN, idx);
    else if (idx < 4096) pack_one(W2, Wp2, N_HID, N_HID, idx - 2048);
    else if (idx < 5120) pack_one(W3, Wp3, N_OUT, N_HID, idx - 4096);
    return;
  }
  int start = (blockIdx.x * 256 + threadIdx.x) * 4;
  int stride = hb * 256 * 4;
  for (int i0 = start; i0 + 4 <= E; i0 += stride) {
    i32x4 d = __builtin_nontemporal_load(reinterpret_cast<const i32x4*>(&dst[i0]));
    u16x4 r;
    r.x = (unsigned short)atomicAdd(&cnt[d.x], 1);
    r.y = (unsigned short)atomicAdd(&cnt[d.y], 1);
    r.z = (unsigned short)atomicAdd(&cnt[d.z], 1);
    r.w = (unsigned short)atomicAdd(&cnt[d.w], 1);
    __builtin_nontemporal_store(r, reinterpret_cast<u16x4*>(&rank[i0]));
  }
  if (blockIdx.x == 0 && threadIdx.x == 0)
    for (int i = E & ~3; i < E; ++i)
      rank[i] = (unsigned short)atomicAdd(&cnt[dst[i]], 1);
}

// ---- single-kernel scan: block b redundantly sums cnt[0..b*512) (L2-resident,
// coalesced), then Hillis-Steele scans its own 512-chunk. Full-grid parallel. ----
#define SCHUNK 512
__global__ __launch_bounds__(SCHUNK) void k_scan_all(
    const int* __restrict__ cnt, int n, int E,
    int* __restrict__ rowptr, float* __restrict__ dinv) {
  __shared__ int sh[SCHUNK];
  int t = threadIdx.x;
  int base = blockIdx.x * SCHUNK;
  int pre = 0;
  for (int i = t; i < base; i += SCHUNK) pre += cnt[i];
  sh[t] = pre;
  __syncthreads();
  for (int o = SCHUNK / 2; o > 0; o >>= 1) {
    if (t < o) sh[t] += sh[t + o];
    __syncthreads();
  }
  int blockpre = sh[0];
  __syncthreads();
  int v = (base + t < n) ? cnt[base + t] : 0;
  sh[t] = v;
  __syncthreads();
  for (int o = 1; o < SCHUNK; o <<= 1) {
    int u = (t >= o) ? sh[t - o] : 0;
    __syncthreads();
    sh[t] += u;
    __syncthreads();
  }
  int i = base + t;
  if (i < n) {
    rowptr[i] = blockpre + sh[t] - v;          // exclusive
    dinv[i] = rsqrtf((float)v + 1.0f);         // +1 self loop
    if (i == n - 1) rowptr[n] = E;
  }
}

// ---------------- MFMA GEMM body (fp32 A via NT loads, dinv scale, out fp16) ----------
__device__ inline void gemm1_body(int bid, const float* __restrict__ A,
                                  const _Float16* __restrict__ Wp,
                                  const float* __restrict__ dinv,
                                  _Float16* __restrict__ out, int M) {
  constexpr int N = N_HID, K = 128, KS = K / 32, NT = N / 16;
  int lane = threadIdx.x & 63;
  int wave = threadIdx.x >> 6;
  int rowbase = bid * 64 + wave * 16;
  int arow = rowbase + (lane & 15);
  int arc = arow < M ? arow : M - 1;
  int k0 = (lane >> 4) * 8;

  f16x8 afrag[KS];
#pragma unroll
  for (int s = 0; s < KS; ++s) {
    f32x4 v0 = __builtin_nontemporal_load(
        reinterpret_cast<const f32x4*>(&A[(size_t)arc * K + s * 32 + k0]));
    f32x4 v1 = __builtin_nontemporal_load(
        reinterpret_cast<const f32x4*>(&A[(size_t)arc * K + s * 32 + k0 + 4]));
    f16x8 f;
    f[0] = (_Float16)v0.x; f[1] = (_Float16)v0.y;
    f[2] = (_Float16)v0.z; f[3] = (_Float16)v0.w;
    f[4] = (_Float16)v1.x; f[5] = (_Float16)v1.y;
    f[6] = (_Float16)v1.z; f[7] = (_Float16)v1.w;
    afrag[s] = f;
  }

  f32x4 acc[NT] = {};
#pragma unroll
  for (int t = 0; t < NT; ++t)
#pragma unroll
    for (int s = 0; s < KS; ++s) {
      f16x8 b = *reinterpret_cast<const f16x8*>(&Wp[((size_t)(t * KS + s) * 64 + lane) * 8]);
      acc[t] = __builtin_amdgcn_mfma_f32_16x16x32_f16(afrag[s], b, acc[t], 0, 0, 0);
    }

  int crow = (lane >> 4) * 4;
  int col = lane & 15;
#pragma unroll
  for (int r = 0; r < 4; ++r) {
    int grow = rowbase + crow + r;
    if (grow < M) {
      float dv = dinv[grow];
#pragma unroll
      for (int t = 0; t < NT; ++t)
        out[(size_t)grow * N + t * 16 + col] = (_Float16)(acc[t][r] * dv);
    }
  }
}

// ---- fill CSR uint16, atomic-free single pass via rank (blocks < fb)
//      + gemm1 riders (blocks >= fb) ----
__global__ __launch_bounds__(256) void k_fill_gemm1(
    const int* __restrict__ src, const int* __restrict__ dst, int E, int n,
    const int* __restrict__ rowptr, const unsigned short* __restrict__ rank,
    unsigned short* __restrict__ csr,
    int fb, const float* __restrict__ x, const _Float16* __restrict__ Wp1,
    const float* __restrict__ dinv, _Float16* __restrict__ hs1) {
  if (blockIdx.x >= fb) {
    gemm1_body((int)blockIdx.x - fb, x, Wp1, dinv, hs1, n);
    return;
  }
  int start = (blockIdx.x * 256 + threadIdx.x) * 4;
  int stride = fb * 256 * 4;
  for (int i0 = start; i0 + 4 <= E; i0 += stride) {
    i32x4 d = __builtin_nontemporal_load(reinterpret_cast<const i32x4*>(&dst[i0]));
    i32x4 sr = __builtin_nontemporal_load(reinterpret_cast<const i32x4*>(&src[i0]));
    u16x4 r = __builtin_nontemporal_load(reinterpret_cast<const u16x4*>(&rank[i0]));
    csr[rowptr[d.x] + r.x] = (unsigned short)sr.x;
    csr[rowptr[d.y] + r.y] = (unsigned short)sr.y;
    csr[rowptr[d.z] + r.z] = (unsigned short)sr.z;
    csr[rowptr[d.w] + r.w] = (unsigned short)sr.w;
  }
  if (blockIdx.x == 0 && threadIdx.x == 0)
    for (int i = E & ~3; i < E; ++i)
      csr[rowptr[dst[i]] + rank[i]] = (unsigned short)src[i];
}

// ---------------- Fused aggregation + GEMM, quarter-wave f16x8 gather ----------------
// in: hs [n][128] (row-scaled); agg+bias+relu -> LDS 16x128 tile -> @ Wp -> out [n][NOUT]
template <int NOUT>
__global__ __launch_bounds__(256) void k_agg_gemm(
    const _Float16* __restrict__ hs, const float* __restrict__ dinv,
    const int* __restrict__ rowptr, const unsigned short* __restrict__ csr,
    const float* __restrict__ bias, const _Float16* __restrict__ Wp,
    _Float16* __restrict__ out, int n, int E) {
  constexpr int D = 128, KS = 4, NT = NOUT / 16, TPW = NT / 4;
  __shared__ __align__(16) _Float16 sm[16][D + 8];  // 272B row stride
  int lane = threadIdx.x & 63, wave = threadIdx.x >> 6;
  int q = lane >> 4;   // quarter-wave: one node per quarter
  int j = lane & 15;   // dim slot [8j, 8j+8)
  int nodebase = blockIdx.x * 16;
  int node = nodebase + wave * 4 + q;
  int cn = min(node, n - 1);
  bool valid = node < n;
  int beg = rowptr[cn], end = valid ? rowptr[cn + 1] : beg;

  float acc[8];
  {
    f16x8 sv = *reinterpret_cast<const f16x8*>(&hs[(size_t)cn * D + 8 * j]);
#pragma unroll
    for (int k = 0; k < 8; ++k) acc[k] = valid ? (float)sv[k] : 0.f;
  }

  for (int e = beg; e < end; e += 4) {
    int idx[4];
    float wt[4];
#pragma unroll
    for (int u = 0; u < 4; ++u) {
      int p = e + u;
      wt[u] = p < end ? 1.f : 0.f;
      idx[u] = csr[min(p, E - 1)];
    }
    f16x8 v[4];
#pragma unroll
    for (int u = 0; u < 4; ++u)
      v[u] = *reinterpret_cast<const f16x8*>(&hs[(size_t)idx[u] * D + 8 * j]);
#pragma unroll
    for (int u = 0; u < 4; ++u)
#pragma unroll
      for (int k = 0; k < 8; ++k)
        acc[k] = fmaf(wt[u], (float)v[u][k], acc[k]);
  }

  // dinv*acc + bias, relu -> LDS tile
  {
    float4 bv0 = *reinterpret_cast<const float4*>(&bias[8 * j]);
    float4 bv1 = *reinterpret_cast<const float4*>(&bias[8 * j + 4]);
    float bp[8] = {bv0.x, bv0.y, bv0.z, bv0.w, bv1.x, bv1.y, bv1.z, bv1.w};
    float dv = dinv[cn];
    f16x8 pv;
#pragma unroll
    for (int k = 0; k < 8; ++k) pv[k] = (_Float16)fmaxf(dv * acc[k] + bp[k], 0.f);
    *reinterpret_cast<f16x8*>(&sm[wave * 4 + q][8 * j]) = pv;
  }
  __syncthreads();

  // MFMA: 16-row tile @ Wp; wave handles TPW n-tiles
  int r = lane & 15, k0 = (lane >> 4) * 8;
  f16x8 af[KS];
#pragma unroll
  for (int s = 0; s < KS; ++s)
    af[s] = *reinterpret_cast<const f16x8*>(&sm[r][s * 32 + k0]);

  f32x4 acc2[TPW] = {};
#pragma unroll
  for (int tt = 0; tt < TPW; ++tt) {
    int t = wave * TPW + tt;
#pragma unroll
    for (int s = 0; s < KS; ++s) {
      f16x8 b = *reinterpret_cast<const f16x8*>(&Wp[((size_t)(t * KS + s) * 64 + lane) * 8]);
      acc2[tt] = __builtin_amdgcn_mfma_f32_16x16x32_f16(af[s], b, acc2[tt], 0, 0, 0);
    }
  }

  int crow = (lane >> 4) * 4, col = lane & 15;
#pragma unroll
  for (int r4 = 0; r4 < 4; ++r4) {
    int gnode = nodebase + crow + r4;
    if (gnode < n) {
      float dv = dinv[gnode];
#pragma unroll
      for (int tt = 0; tt < TPW; ++tt)
        out[(size_t)gnode * NOUT + (wave * TPW + tt) * 16 + col] =
            (_Float16)(acc2[tt][r4] * dv);
    }
  }
}

// ---------------- Aggregation D=64 + log_softmax, eighth-wave f16x8 gather ----------
__global__ __launch_bounds__(256) void k_agg64_lsm(
    const _Float16* __restrict__ hs, const float* __restrict__ dinv,
    const int* __restrict__ rowptr, const unsigned short* __restrict__ csr,
    const float* __restrict__ bias, float* __restrict__ out, int n, int E) {
  constexpr int D = 64;
  int lane = threadIdx.x & 63, wave = threadIdx.x >> 6;
  int g = lane >> 3;   // eighth-wave group: one node per group
  int j = lane & 7;    // dim slot [8j, 8j+8)
  int node = blockIdx.x * 32 + wave * 8 + g;
  int cn = min(node, n - 1);
  bool valid = node < n;
  int beg = rowptr[cn], end = valid ? rowptr[cn + 1] : beg;

  float acc[8];
  {
    f16x8 sv = *reinterpret_cast<const f16x8*>(&hs[(size_t)cn * D + 8 * j]);
#pragma unroll
    for (int k = 0; k < 8; ++k) acc[k] = valid ? (float)sv[k] : 0.f;
  }

  for (int e = beg; e < end; e += 4) {
    int idx[4];
    float wt[4];
#pragma unroll
    for (int u = 0; u < 4; ++u) {
      int p = e + u;
      wt[u] = p < end ? 1.f : 0.f;
      idx[u] = csr[min(p, E - 1)];
    }
    f16x8 v[4];
#pragma unroll
    for (int u = 0; u < 4; ++u)
      v[u] = *reinterpret_cast<const f16x8*>(&hs[(size_t)idx[u] * D + 8 * j]);
#pragma unroll
    for (int u = 0; u < 4; ++u)
#pragma unroll
      for (int k = 0; k < 8; ++k)
        acc[k] = fmaf(wt[u], (float)v[u][k], acc[k]);
  }

  float dv = dinv[cn];
  float val[8];
  {
    float4 bv0 = *reinterpret_cast<const float4*>(&bias[8 * j]);
    float4 bv1 = *reinterpret_cast<const float4*>(&bias[8 * j + 4]);
    float bp[8] = {bv0.x, bv0.y, bv0.z, bv0.w, bv1.x, bv1.y, bv1.z, bv1.w};
#pragma unroll
    for (int k = 0; k < 8; ++k) val[k] = dv * acc[k] + bp[k];
  }

  // log_softmax: 8 dims/lane x 8 lanes (xor offsets < 8 stay in-group)
  float m = val[0];
#pragma unroll
  for (int k = 1; k < 8; ++k) m = fmaxf(m, val[k]);
#pragma unroll
  for (int o = 4; o > 0; o >>= 1) m = fmaxf(m, __shfl_xor(m, o));
  float ss = 0.f;
#pragma unroll
  for (int k = 0; k < 8; ++k) ss += expf(val[k] - m);
#pragma unroll
  for (int o = 4; o > 0; o >>= 1) ss += __shfl_xor(ss, o);
  float lse = m + logf(ss);

  if (valid) {
    f32x4 o0 = {val[0] - lse, val[1] - lse, val[2] - lse, val[3] - lse};
    f32x4 o1 = {val[4] - lse, val[5] - lse, val[6] - lse, val[7] - lse};
    __builtin_nontemporal_store(o0, reinterpret_cast<f32x4*>(&out[(size_t)node * D + 8 * j]));
    __builtin_nontemporal_store(o1, reinterpret_cast<f32x4*>(&out[(size_t)node * D + 8 * j + 4]));
  }
}

// ---------------- launch ----------------
extern "C" void kernel_launch(void* const* d_in, const int* in_sizes, int n_in,
                              void* d_out, int out_size, void* d_ws, size_t ws_size,
                              hipStream_t stream) {
  const float* x  = (const float*)d_in[0];
  const float* W1 = (const float*)d_in[1];
  const float* b1 = (const float*)d_in[2];
  const float* W2 = (const float*)d_in[3];
  const float* b2 = (const float*)d_in[4];
  const float* W3 = (const float*)d_in[5];
  const float* b3 = (const float*)d_in[6];
  const int*   ei = (const int*)d_in[7];

  int n = in_sizes[0] / N_IN;   // 50000 (< 65536: uint16 csr/rank)
  int E = in_sizes[7] / 2;
  const int* src = ei;
  const int* dst = ei + E;

  char* w = (char*)d_ws;
  size_t off = 0;
  auto alloc = [&](size_t bytes) -> void* {
    void* p = w + off;
    off = (off + bytes + 255) & ~(size_t)255;
    return p;
  };
  _Float16* hs1 = (_Float16*)alloc((size_t)n * N_HID * sizeof(_Float16));
  _Float16* hs2 = (_Float16*)alloc((size_t)n * N_HID * sizeof(_Float16));
  _Float16* hs3 = (_Float16*)alloc((size_t)n * N_OUT * sizeof(_Float16));
  _Float16* Wp1 = (_Float16*)alloc((size_t)N_IN * N_HID * sizeof(_Float16));
  _Float16* Wp2 = (_Float16*)alloc((size_t)N_HID * N_HID * sizeof(_Float16));
  _Float16* Wp3 = (_Float16*)alloc((size_t)N_HID * N_OUT * sizeof(_Float16));
  float* dinv = (float*)alloc((size_t)n * sizeof(float));
  int* cnt = (int*)alloc((size_t)n * sizeof(int));
  int* rowptr = (int*)alloc((size_t)(n + 1) * sizeof(int));
  unsigned short* csr = (unsigned short*)alloc((size_t)E * sizeof(unsigned short));
  unsigned short* rank = (unsigned short*)alloc((size_t)E * sizeof(unsigned short));

  // ---- CSR by dst (+ degrees, dinv, per-edge rank) + weight pack + layer-1 GEMM ----
  hipMemsetAsync(cnt, 0, (size_t)n * sizeof(int), stream);
  int hb = min((E / 4 + 255) / 256, 1024);
  k_hist_rank_pack<<<hb + 20, 256, 0, stream>>>(dst, E, n, cnt, rank, hb,
                                                W1, W2, W3, Wp1, Wp2, Wp3);
  int nb = (n + SCHUNK - 1) / SCHUNK;
  k_scan_all<<<nb, SCHUNK, 0, stream>>>(cnt, n, E, rowptr, dinv);
  int gb = (n + 63) / 64;
  k_fill_gemm1<<<hb + gb, 256, 0, stream>>>(src, dst, E, n, rowptr, rank, csr, hb,
                                            x, Wp1, dinv, hs1);

  int ab = (n + 15) / 16;
  int ab64 = (n + 31) / 32;
  k_agg_gemm<N_HID><<<ab, 256, 0, stream>>>(hs1, dinv, rowptr, csr, b1, Wp2, hs2, n, E);
  k_agg_gemm<N_OUT><<<ab, 256, 0, stream>>>(hs2, dinv, rowptr, csr, b2, Wp3, hs3, n, E);
  k_agg64_lsm<<<ab64, 256, 0, stream>>>(hs3, dinv, rowptr, csr, b3, (float*)d_out, n, E);
}